// Round 20
// baseline (78.374 us; speedup 1.0000x reference)
//
#include <hip/hip_runtime.h>

static constexpr int DIN = 512;
static constexpr int DOUT = 256;
static constexpr int NB = 64;    // deg-histogram blocks (replicas)
static constexpr int CAP = 128;  // bucket capacity per dst (Poisson(32): P(>128)~1e-17)
static constexpr int NNODE = 8192;
static constexpr float DEG_SCALE = 1048576.0f;  // 2^20 fixed point
static constexpr float DEG_INV = 1.0f / 1048576.0f;

typedef __attribute__((ext_vector_type(8))) short short8;
typedef __attribute__((ext_vector_type(4))) float f32x4;
typedef __attribute__((ext_vector_type(2))) unsigned int u32x2;
typedef __attribute__((ext_vector_type(4))) unsigned int u32x4;

__device__ inline unsigned short f2bf(float f) {
  unsigned int b = __float_as_uint(f);
  unsigned int r = (b + 0x7fffu + ((b >> 16) & 1u)) >> 16;
  return (unsigned short)r;
}
__device__ inline float bf_lo(unsigned int packed) { return __uint_as_float(packed << 16); }
__device__ inline float bf_hi(unsigned int packed) { return __uint_as_float(packed & 0xffff0000u); }

__device__ inline short8 cvt8(const f32x4 a, const f32x4 b) {
  short8 o;
  o[0] = (short)f2bf(a[0]); o[1] = (short)f2bf(a[1]);
  o[2] = (short)f2bf(a[2]); o[3] = (short)f2bf(a[3]);
  o[4] = (short)f2bf(b[0]); o[5] = (short)f2bf(b[1]);
  o[6] = (short)f2bf(b[2]); o[7] = (short)f2bf(b[3]);
  return o;
}

// ---- D1: blocks [0,NB): deg histogram (LDS atomics only -> deg_rep[b][n])
//          blocks [NB,NB+512): GEMM, A AND B inline f32->bf16; first 32 also
//          zero cursor[]. No device atomics anywhere in this dispatch.
__global__ __launch_bounds__(256) void k_d1(
    const int* __restrict__ ei, const float* __restrict__ ew,
    const float* __restrict__ x, const float* __restrict__ W,
    int* __restrict__ deg_rep, int* __restrict__ cursor,
    unsigned short* __restrict__ h1b, int E) {
  if (blockIdx.x < NB) {
    __shared__ int s_deg[NNODE];  // 32 KB
    const int b = blockIdx.x;
    const int t = threadIdx.x;
    for (int i = t; i < NNODE; i += 256) s_deg[i] = 0;
    __syncthreads();
    const int base = b * (E / NB);
    const int iters = (E / NB) / 256;  // 16
    for (int i = 0; i < iters; ++i) {
      const int e = base + i * 256 + t;
      int sv = __builtin_nontemporal_load(ei + e);
      float w = __builtin_nontemporal_load(ew + e);
      atomicAdd(&s_deg[sv], __float2int_rn(w * DEG_SCALE));
    }
    __syncthreads();
    for (int i = t; i < NNODE; i += 256) deg_rep[b * NNODE + i] = s_deg[i];
    return;
  }
  const int g = blockIdx.x - NB;  // 0..511
  if (g < 32) cursor[g * 256 + threadIdx.x] = 0;  // zero before D2's bin
  // ---- GEMM: rows bm..bm+15, wave -> 64-col strip of 256; UNSCALED h1b ----
  const int lane = threadIdx.x & 63;
  const int wv = threadIdx.x >> 6;
  const int bm = g * 16;
  const int colb = wv * 64;
  const int r = lane & 15;
  const int kg = lane >> 4;
  f32x4 acc[4] = {};
  const float* arow = x + (size_t)(bm + r) * DIN + kg * 8;
  const float* brow0 = W + (size_t)(colb + r) * DIN + kg * 8;
#pragma unroll
  for (int k0 = 0; k0 < DIN; k0 += 32) {
    f32x4 a0 = *(const f32x4*)(arow + k0);
    f32x4 a1 = *(const f32x4*)(arow + k0 + 4);
    short8 av = cvt8(a0, a1);
#pragma unroll
    for (int nt = 0; nt < 4; ++nt) {
      const float* bp = brow0 + (size_t)nt * 16 * DIN + k0;
      f32x4 b0 = *(const f32x4*)bp;
      f32x4 b1 = *(const f32x4*)(bp + 4);
      short8 bv = cvt8(b0, b1);
      acc[nt] = __builtin_amdgcn_mfma_f32_16x16x32_bf16(av, bv, acc[nt], 0, 0, 0);
    }
  }
#pragma unroll
  for (int i = 0; i < 4; ++i) {
    int row = bm + kg * 4 + i;
#pragma unroll
    for (int nt = 0; nt < 4; ++nt) {
      h1b[(size_t)row * DOUT + colb + nt * 16 + r] = f2bf(acc[nt][i]);
    }
  }
}

// ---- D2: blocks [0,32): sdeg fold (64 replicas -> rsqrt(1+deg))
//          blocks [32,32+1024): bin — the ONLY device atomics, isolated here
__global__ __launch_bounds__(256) void k_d2(
    const int* __restrict__ ei, const float* __restrict__ ew,
    const int* __restrict__ deg_rep, float* __restrict__ sdeg,
    int* __restrict__ cursor, uint2* __restrict__ bucket, int E) {
  const int blk = blockIdx.x;
  if (blk < 32) {
    const int i = blk * 256 + threadIdx.x;
    int sum = 0;
#pragma unroll
    for (int r = 0; r < NB; ++r) sum += deg_rep[r * NNODE + i];
    sdeg[i] = __frsqrt_rn(1.0f + (float)sum * DEG_INV);
    return;
  }
  const int e = (blk - 32) * 256 + threadIdx.x;
  if (e >= E) return;
  int srcv = __builtin_nontemporal_load(ei + e);
  int dstv = __builtin_nontemporal_load(ei + E + e);
  float w = __builtin_nontemporal_load(ew + e);
  int pos = atomicAdd(&cursor[dstv], 1);
  if (pos < CAP) {
    u32x2 v;
    v[0] = (unsigned)srcv;
    v[1] = __float_as_uint(w);
    __builtin_nontemporal_store(v, (u32x2*)(bucket + (size_t)dstv * CAP + pos));
  }
}

// ---- D3: gather (R13/R14-proven shape): one wave/dst, 32 col-lanes x 2
// halves, 8-deep row-load batches; s folded via sdeg lookups.
// out[d] = s[d]*( s[d]*h1[d] + sum_e w_e * s[src_e] * h1[src_e] )
__global__ __launch_bounds__(256, 4) void k_gather(
    const unsigned short* __restrict__ h1b, const float* __restrict__ sdeg,
    const int* __restrict__ cursor, const uint2* __restrict__ bucket,
    float* __restrict__ out) {
  const int lane = threadIdx.x & 63;
  const int wv = threadIdx.x >> 6;
  const int dst = blockIdx.x * 4 + wv;
  const int cl = lane & 31;    // column-lane: cols cl*8 .. cl*8+7
  const int half = lane >> 5;  // which edge of a pair
  const int cnt = min(cursor[dst], CAP);

  const u32x4 selfv = *(const u32x4*)(h1b + (size_t)dst * DOUT + cl * 8);
  const float sd = sdeg[dst];

  float acc[8] = {};

  for (int base = 0; base < cnt; base += 64) {
    const int c = min(64, cnt - base);
    int sv = 0;
    float wl = 0.f;
    if (lane < c) {
      u32x2 ev = __builtin_nontemporal_load(
          (const u32x2*)(bucket + (size_t)dst * CAP + base + lane));
      sv = (int)ev[0];
      wl = __uint_as_float(ev[1]) * sdeg[sv];
    }
    const int npair = ((c + 15) >> 4) << 3;  // pad to mult of 16 edges
    for (int j = 0; j < npair; j += 8) {
      u32x4 rbuf[8];
#pragma unroll
      for (int u = 0; u < 8; ++u) {
        int src = __shfl(sv, 2 * (j + u) + half);
        rbuf[u] = *(const u32x4*)(h1b + (size_t)src * DOUT + cl * 8);
      }
#pragma unroll
      for (int u = 0; u < 8; ++u) {
        float w = __shfl(wl, 2 * (j + u) + half);
        acc[0] = fmaf(w, bf_lo(rbuf[u][0]), acc[0]);
        acc[1] = fmaf(w, bf_hi(rbuf[u][0]), acc[1]);
        acc[2] = fmaf(w, bf_lo(rbuf[u][1]), acc[2]);
        acc[3] = fmaf(w, bf_hi(rbuf[u][1]), acc[3]);
        acc[4] = fmaf(w, bf_lo(rbuf[u][2]), acc[4]);
        acc[5] = fmaf(w, bf_hi(rbuf[u][2]), acc[5]);
        acc[6] = fmaf(w, bf_lo(rbuf[u][3]), acc[6]);
        acc[7] = fmaf(w, bf_hi(rbuf[u][3]), acc[7]);
      }
    }
  }

#pragma unroll
  for (int k = 0; k < 8; ++k) acc[k] += __shfl_xor(acc[k], 32);

  if (half == 0) {
    f32x4 o0v, o1v;
    o0v[0] = sd * fmaf(sd, bf_lo(selfv[0]), acc[0]);
    o0v[1] = sd * fmaf(sd, bf_hi(selfv[0]), acc[1]);
    o0v[2] = sd * fmaf(sd, bf_lo(selfv[1]), acc[2]);
    o0v[3] = sd * fmaf(sd, bf_hi(selfv[1]), acc[3]);
    o1v[0] = sd * fmaf(sd, bf_lo(selfv[2]), acc[4]);
    o1v[1] = sd * fmaf(sd, bf_hi(selfv[2]), acc[5]);
    o1v[2] = sd * fmaf(sd, bf_lo(selfv[3]), acc[6]);
    o1v[3] = sd * fmaf(sd, bf_hi(selfv[3]), acc[7]);
    float* op = out + (size_t)dst * DOUT + cl * 8;
    __builtin_nontemporal_store(o0v, (f32x4*)op);
    __builtin_nontemporal_store(o1v, (f32x4*)(op + 4));
  }
}

extern "C" void kernel_launch(void* const* d_in, const int* in_sizes, int n_in,
                              void* d_out, int out_size, void* d_ws, size_t ws_size,
                              hipStream_t stream) {
  const float* x = (const float*)d_in[0];
  const int* ei = (const int*)d_in[1];  // [2, E]: row0 = src, row1 = dst
  const float* ew = (const float*)d_in[2];
  const float* W = (const float*)d_in[3];
  float* out = (float*)d_out;

  const int n = in_sizes[0] / DIN;  // 8192
  const int E = in_sizes[2];        // 262144

  char* p = (char*)d_ws;
  auto alloc = [&](size_t bytes) {
    char* q = p;
    p += (bytes + 255) & ~(size_t)255;
    return q;
  };
  unsigned short* h1b = (unsigned short*)alloc((size_t)n * DOUT * 2);
  int* deg_rep = (int*)alloc((size_t)NB * NNODE * 4);
  int* cursor  = (int*)alloc((size_t)n * 4);
  float* sdeg  = (float*)alloc((size_t)n * 4);
  uint2* bucket = (uint2*)alloc((size_t)n * CAP * 8);

  const int GB = n / 16;  // 512 GEMM blocks

  k_d1<<<NB + GB, 256, 0, stream>>>(ei, ew, x, W, deg_rep, cursor, h1b, E);
  k_d2<<<32 + (E + 255) / 256, 256, 0, stream>>>(ei, ew, deg_rep, sdeg,
                                                 cursor, bucket, E);
  k_gather<<<n / 4, 256, 0, stream>>>(h1b, sdeg, cursor, bucket, out);
}